// Round 8
// baseline (598.345 us; speedup 1.0000x reference)
//
#include <hip/hip_runtime.h>
#include <hip/hip_bf16.h>
#include <stdint.h>

#define IN_F 4096
#define OUT_F 4096
#define M_TOTAL 8192   // 4 * 2048
#define NKT 64         // IN_F / 64

typedef __hip_bfloat16 bf16;
typedef __attribute__((ext_vector_type(8))) short bf16x8;   // 8 bf16 (4 VGPRs)
typedef __attribute__((ext_vector_type(4))) float f32x4;    // MFMA accumulator

// ---------------- kernel 1: dequant packed int4 -> bf16 W (OUT_F x IN_F row-major)
__global__ __launch_bounds__(256) void dequant_w(const int* __restrict__ qweight,
                                                 const float* __restrict__ scales,
                                                 const int* __restrict__ qzeros,
                                                 bf16* __restrict__ Wb) {
    int idx = blockIdx.x * 256 + threadIdx.x;       // one int32 (8 nibbles) per thread
    int o = idx >> 9;                               // / (IN_F/8)
    int j = idx & 511;
    int g = j >> 4;                                 // (j*8)/128
    int qw = qweight[idx];
    float s = scales[g * OUT_F + o];
    float z = (float)qzeros[g * OUT_F + o];
    union { bf16 h[8]; uint4 q; } out;
#pragma unroll
    for (int b = 0; b < 8; ++b) {
        float w = (float)((qw >> (4 * b)) & 15);
        out.h[b] = __float2bfloat16((w - z) * s);
    }
    *reinterpret_cast<uint4*>(Wb + ((size_t)o * IN_F + j * 8)) = out.q;
}

// ---------------- kernel 2: 256x256 8-phase bf16 GEMM, A read DIRECTLY from fp32 x
// (reg-staged global_load_dwordx4 -> cvt -> ds_write_b128; Xb eliminated).
// B path unchanged: global_load_lds from pre-dequantized Wb (pre-swizzled source).
// The A-LDS image is byte-identical to the gload_lds version (lane loads
// pre-swizzled fp32 cols, writes linear lane*16), so fragment reads/MFMA/epilogue
// are untouched from the proven round-6 kernel (237us).
// C(MxN) = x(MxK)*W(NxK)^T + bias. 8 waves (2M x 4N), per-wave 128x64 out.
// Fragment rows: A = MH*128 + wr*64 + m4*16; B = NH*128 + wc*32 + n2*16.
// LDS 128 KiB: buf b at b*65536; A h0/h1 @ +0/+16384, B h0/h1 @ +32768/+49152.
// Swizzle: 16B slot s of row r stored at s ^ (r & 7); pre-swizzled global src.

__device__ __forceinline__ void gload16(const bf16* g, char* l) {
    __builtin_amdgcn_global_load_lds(
        (const __attribute__((address_space(1))) void*)g,
        (__attribute__((address_space(3))) void*)l, 16, 0, 0);
}

// Stage B: 128 rows x 64 cols bf16 (16 KiB): 8 waves x 2 gload x 64 lanes x 16 B.
__device__ __forceinline__ void stage_half(const bf16* __restrict__ Gt,
                                           char* ldsb, int wave, int lane) {
    const int slog8 = ((lane & 7) ^ (lane >> 3)) * 8;   // pre-swizzled 16B slot
#pragma unroll
    for (int j = 0; j < 2; ++j) {
        int r = wave * 16 + j * 8 + (lane >> 3);        // r & 7 == lane>>3
        gload16(Gt + (size_t)r * IN_F + slog8, ldsb + (wave * 2 + j) * 1024);
    }
}

// A staging, issue side: 4x global_load_dwordx4 of fp32 x (pre-swizzled cols).
// Xg points at (row0, kcol0); row stride IN_F (f32).
__device__ __forceinline__ void issueA(const float* __restrict__ Xg,
                                       int wave, int lane, float4 av[2][2]) {
    const int slog8 = ((lane & 7) ^ (lane >> 3)) * 8;
#pragma unroll
    for (int jj = 0; jj < 2; ++jj) {
        const float* p = Xg + (size_t)(wave * 16 + jj * 8 + (lane >> 3)) * IN_F + slog8;
        av[jj][0] = *reinterpret_cast<const float4*>(p);
        av[jj][1] = *reinterpret_cast<const float4*>(p + 4);
    }
}

// A staging, write side: cvt to bf16 and ds_write_b128 at the linear dest
// (same bytes gload_lds would have written).  Compiler inserts the counted
// vmcnt before the first use of av.
__device__ __forceinline__ void writeA(char* ldsb, int wave, int lane,
                                       const float4 av[2][2]) {
#pragma unroll
    for (int jj = 0; jj < 2; ++jj) {
        union { bf16 h[8]; uint4 q; } u;
        u.h[0] = __float2bfloat16(av[jj][0].x); u.h[1] = __float2bfloat16(av[jj][0].y);
        u.h[2] = __float2bfloat16(av[jj][0].z); u.h[3] = __float2bfloat16(av[jj][0].w);
        u.h[4] = __float2bfloat16(av[jj][1].x); u.h[5] = __float2bfloat16(av[jj][1].y);
        u.h[6] = __float2bfloat16(av[jj][1].z); u.h[7] = __float2bfloat16(av[jj][1].w);
        *reinterpret_cast<uint4*>(ldsb + (wave * 2 + jj) * 1024 + lane * 16) = u.q;
    }
}

#define BARRIER() do { asm volatile("" ::: "memory"); \
                       __builtin_amdgcn_s_barrier();  \
                       asm volatile("" ::: "memory"); } while (0)
#define LGKM0()   asm volatile("s_waitcnt lgkmcnt(0)" ::: "memory")
#define VMCNT0()  asm volatile("s_waitcnt vmcnt(0)" ::: "memory")

// A fragment rows: MH*128 + wr*64 + m4*16 + l15
#define LDA_SET(DST, BUF, MH) do {                                              \
  _Pragma("unroll") for (int m4 = 0; m4 < 4; ++m4)                              \
  _Pragma("unroll") for (int kk = 0; kk < 2; ++kk)                              \
    DST[m4][kk] = *reinterpret_cast<const bf16x8*>(sm + (BUF) * 65536           \
        + (((MH) * 128 + wr * 64 + m4 * 16 + l15) << 7)                         \
        + ((((kk << 2) + lq) ^ l7) << 4));                                      \
} while (0)

// B fragment rows: NH*128 + wc*32 + n2*16 + l15
#define LDB_SET(DST, BUF, NH) do {                                              \
  _Pragma("unroll") for (int n2 = 0; n2 < 2; ++n2)                              \
  _Pragma("unroll") for (int kk = 0; kk < 2; ++kk)                              \
    DST[n2][kk] = *reinterpret_cast<const bf16x8*>(sm + (BUF) * 65536 + 32768   \
        + (((NH) * 128 + wc * 32 + n2 * 16 + l15) << 7)                         \
        + ((((kk << 2) + lq) ^ l7) << 4));                                      \
} while (0)

#define MMA_Q(AF, BFR, MH, NH) do {                                             \
  __builtin_amdgcn_s_setprio(1);                                                \
  _Pragma("unroll") for (int m4 = 0; m4 < 4; ++m4)                              \
  _Pragma("unroll") for (int n2 = 0; n2 < 2; ++n2)                              \
  _Pragma("unroll") for (int kk = 0; kk < 2; ++kk)                              \
    acc[(MH) * 4 + m4][(NH) * 2 + n2] = __builtin_amdgcn_mfma_f32_16x16x32_bf16(\
        AF[m4][kk], BFR[n2][kk], acc[(MH) * 4 + m4][(NH) * 2 + n2], 0, 0, 0);   \
  __builtin_amdgcn_s_setprio(0);                                                \
} while (0)

__global__ __launch_bounds__(512, 2) void gemm256(const float* __restrict__ X,  // M x K fp32
                                                  const bf16* __restrict__ B,   // N x K bf16
                                                  const float* __restrict__ bias,
                                                  float* __restrict__ C) {
    extern __shared__ char sm[];
    const int tid  = threadIdx.x;
    const int wave = tid >> 6;
    const int lane = tid & 63;
    const int wr   = wave >> 2;       // 2 M-rows of waves
    const int wc   = wave & 3;        // 4 N-cols of waves
    const int l15  = lane & 15;
    const int lq   = lane >> 4;
    const int l7   = lane & 7;

    // XCD-aware bijective swizzle (nwg = 512, % 8 == 0)
    const int nwg = gridDim.x;
    const int cpx = nwg >> 3;
    const int wg  = blockIdx.x;
    const int swz = (wg & 7) * cpx + (wg >> 3);
    const int bm  = swz >> 4;         // 16 n-tiles (4096/256)
    const int bn  = swz & 15;
    const int m0  = bm * 256;
    const int n0  = bn * 256;

    const float* X0 = X + (size_t)m0 * IN_F;          // A h0 rows (fp32)
    const float* X1 = X + (size_t)(m0 + 128) * IN_F;  // A h1 rows
    const bf16*  B0 = B + (size_t)n0 * IN_F;
    const bf16*  B1 = B + (size_t)(n0 + 128) * IN_F;

    f32x4 acc[8][4];
#pragma unroll
    for (int m = 0; m < 8; ++m)
#pragma unroll
        for (int n = 0; n < 4; ++n) acc[m][n] = (f32x4){0.f, 0.f, 0.f, 0.f};

    bf16x8 af0[4][2], af1[4][2], bfr0[2][2], bfr1[2][2];
    float4 avH0[2][2], avH1[2][2];

    // ---- prologue: tile0 A (reg-staged) + tile0 B + tile1 {A reg, Bh0}
    issueA(X0, wave, lane, avH0);                  // A(0) h0
    issueA(X1, wave, lane, avH1);                  // A(0) h1
    stage_half(B0,      sm + 32768, wave, lane);   // B(0) h0
    stage_half(B1,      sm + 49152, wave, lane);   // B(0) h1
    stage_half(B0 + 64, sm + 98304, wave, lane);   // B(1) h0
    writeA(sm + 0,     wave, lane, avH0);          // auto vmcnt gates
    writeA(sm + 16384, wave, lane, avH1);
    issueA(X0 + 64, wave, lane, avH0);             // A(1) h0
    issueA(X1 + 64, wave, lane, avH1);             // A(1) h1
    writeA(sm + 65536, wave, lane, avH0);
    writeA(sm + 81920, wave, lane, avH1);          // final auto-wait drains B(0) too
    LGKM0();                                       // ds_writes complete before barrier
    BARRIER();
    // pre-read P1's fragments (buf0 t0)
    LDA_SET(af0, 0, 0);
    LDB_SET(bfr0, 0, 0);

    for (int i = 0; i < 32; ++i) {
        const int t1 = 2 * i + 1;
        const int t2 = 2 * i + 2;
        const int t3 = 2 * i + 3;
        const bool gg = (i < 31);

        // ---- P1: MFMA t0 q1; issue A(t2)h0; stage buf1.Bh1(t1); pre-read af1.
        if (gg) issueA(X0 + t2 * 64, wave, lane, avH0);
        stage_half(B1 + t1 * 64, sm + 114688, wave, lane);
        BARRIER(); LGKM0();
        MMA_Q(af0, bfr0, 0, 0);
        LDA_SET(af1, 0, 1);                                      // for P2
        BARRIER();
        // ---- P2: q2; issue A(t2)h1; write A(t2)h0 -> buf0.Ah0 (free since prev P8 read);
        //          pre-read bfr1.
        if (gg) issueA(X1 + t2 * 64, wave, lane, avH1);
        BARRIER(); LGKM0();
        MMA_Q(af1, bfr0, 1, 0);
        if (gg) writeA(sm + 0, wave, lane, avH0);
        LDB_SET(bfr1, 0, 1);                                     // for P3
        BARRIER();
        // ---- P3: q3; stage buf0.Bh0(t2); write A(t2)h1 -> buf0.Ah1 (read P1).
        if (gg) stage_half(B0 + t2 * 64, sm + 32768, wave, lane);
        BARRIER(); LGKM0();
        MMA_Q(af0, bfr1, 0, 1);
        if (gg) writeA(sm + 16384, wave, lane, avH1);
        BARRIER();
        // ---- P4: q4; tail drain; pre-read buf1 t1 fragments.
        BARRIER(); LGKM0();
        MMA_Q(af1, bfr1, 1, 1);
        if (!gg) VMCNT0();                 // tail: gate B(t1)h1 (no auto-waits left)
        LDA_SET(af0, 1, 0);                                      // for P5
        LDB_SET(bfr0, 1, 0);
        BARRIER();

        // ---- P5: t1 q1; issue A(t3)h0; stage buf0.Bh1(t2); pre-read af1.
        if (gg) issueA(X0 + t3 * 64, wave, lane, avH0);
        if (gg) stage_half(B1 + t2 * 64, sm + 49152, wave, lane);
        BARRIER(); LGKM0();
        MMA_Q(af0, bfr0, 0, 0);
        LDA_SET(af1, 1, 1);                                      // for P6
        BARRIER();
        // ---- P6: q2; issue A(t3)h1; write A(t3)h0 -> buf1.Ah0 (read P4); pre-read bfr1.
        if (gg) issueA(X1 + t3 * 64, wave, lane, avH1);
        BARRIER(); LGKM0();
        MMA_Q(af1, bfr0, 1, 0);
        if (gg) writeA(sm + 65536, wave, lane, avH0);
        LDB_SET(bfr1, 1, 1);                                     // for P7
        BARRIER();
        // ---- P7: q3; stage buf1.Bh0(t3); write A(t3)h1 -> buf1.Ah1 (read P5).
        if (gg) stage_half(B0 + t3 * 64, sm + 98304, wave, lane);
        BARRIER(); LGKM0();
        MMA_Q(af0, bfr1, 0, 1);
        if (gg) writeA(sm + 81920, wave, lane, avH1);
        BARRIER();
        // ---- P8: q4; pre-read buf0 t2 fragments (B(t2)h0 gated by P7's auto-wait).
        BARRIER(); LGKM0();
        MMA_Q(af1, bfr1, 1, 1);
        if (gg) {
            LDA_SET(af0, 0, 0);                                  // for next-iter P1
            LDB_SET(bfr0, 0, 0);
        }
        BARRIER();
    }

    // ---- epilogue (round-6 proven): C/D col = lane&15, row = (lane>>4)*4 + reg
    const int crow_base = m0 + wr * 64 + lq * 4;
    const int ccol_base = n0 + wc * 32 + l15;
#pragma unroll
    for (int n = 0; n < 4; ++n) {
        const int NH = n >> 1, n2 = n & 1;
        const int col = ccol_base + NH * 128 + n2 * 16;
        float bv = bias[col];
#pragma unroll
        for (int m = 0; m < 8; ++m) {
            const int MH = m >> 2, m4 = m & 3;
            const int row = crow_base + MH * 128 + m4 * 16;
#pragma unroll
            for (int r = 0; r < 4; ++r)
                C[(size_t)(row + r) * OUT_F + col] = acc[m][n][r] + bv;
        }
    }
}

// ---------------- fallback: fp32 tiled GEMM with on-the-fly dequant (ws too small)
__global__ __launch_bounds__(256) void fallback_gemm(const float* __restrict__ x,
                                                     const int* __restrict__ qweight,
                                                     const float* __restrict__ scales,
                                                     const int* __restrict__ qzeros,
                                                     const float* __restrict__ bias,
                                                     float* __restrict__ out) {
    __shared__ float Asf[64][65];
    __shared__ float Bsf[64][65];
    int bm = blockIdx.x >> 6;
    int bn = blockIdx.x & 63;
    int m0 = bm * 64, n0 = bn * 64;
    int t  = threadIdx.x;
    int tr = t >> 4, tc = t & 15;
    float acc[4][4] = {};
    for (int kt = 0; kt < IN_F; kt += 64) {
#pragma unroll
        for (int i = 0; i < 4; ++i) {
            int idx = t + i * 256;
            int r = idx >> 4, c4 = idx & 15;
            float4 v = *reinterpret_cast<const float4*>(x + (size_t)(m0 + r) * IN_F + kt + c4 * 4);
            Asf[r][c4 * 4 + 0] = v.x; Asf[r][c4 * 4 + 1] = v.y;
            Asf[r][c4 * 4 + 2] = v.z; Asf[r][c4 * 4 + 3] = v.w;
        }
#pragma unroll
        for (int i = 0; i < 2; ++i) {
            int idx = t + i * 256;
            int r = idx >> 3, k8 = idx & 7;
            int kk = kt + k8 * 8;
            int o  = n0 + r;
            int qw = qweight[(size_t)o * (IN_F / 8) + (kk >> 3)];
            int g  = kk >> 7;
            float s = scales[g * OUT_F + o];
            float z = (float)qzeros[g * OUT_F + o];
#pragma unroll
            for (int b = 0; b < 8; ++b)
                Bsf[r][k8 * 8 + b] = ((float)((qw >> (4 * b)) & 15) - z) * s;
        }
        __syncthreads();
#pragma unroll 8
        for (int k = 0; k < 64; ++k) {
            float a[4], bb[4];
#pragma unroll
            for (int i = 0; i < 4; ++i) a[i] = Asf[tr * 4 + i][k];
#pragma unroll
            for (int j = 0; j < 4; ++j) bb[j] = Bsf[tc * 4 + j][k];
#pragma unroll
            for (int i = 0; i < 4; ++i)
#pragma unroll
                for (int j = 0; j < 4; ++j) acc[i][j] += a[i] * bb[j];
        }
        __syncthreads();
    }
#pragma unroll
    for (int i = 0; i < 4; ++i) {
        int row = m0 + tr * 4 + i;
#pragma unroll
        for (int j = 0; j < 4; ++j) {
            int col = n0 + tc * 4 + j;
            out[(size_t)row * OUT_F + col] = acc[i][j] + bias[col];
        }
    }
}

extern "C" void kernel_launch(void* const* d_in, const int* in_sizes, int n_in,
                              void* d_out, int out_size, void* d_ws, size_t ws_size,
                              hipStream_t stream) {
    (void)in_sizes; (void)n_in; (void)out_size;
    const float* x       = (const float*)d_in[0];
    const int*   qweight = (const int*)d_in[1];
    const float* scales  = (const float*)d_in[2];
    const int*   qzeros  = (const int*)d_in[3];
    const float* bias    = (const float*)d_in[4];
    float* out = (float*)d_out;

    const size_t needW = (size_t)OUT_F * IN_F * sizeof(bf16);   // 32 MB

    if (ws_size >= needW) {
        bf16* Wb = (bf16*)d_ws;
        dequant_w<<<(OUT_F * (IN_F / 8)) / 256, 256, 0, stream>>>(qweight, scales, qzeros, Wb);
        gemm256<<<(M_TOTAL / 256) * (OUT_F / 256), 512, 131072, stream>>>(x, Wb, bias, out);
    } else {
        fallback_gemm<<<(M_TOTAL / 64) * (OUT_F / 64), 256, 0, stream>>>(
            x, qweight, scales, qzeros, bias, out);
    }
}

// Round 9
// 273.579 us; speedup vs baseline: 2.1871x; 2.1871x over previous
//
#include <hip/hip_runtime.h>
#include <hip/hip_bf16.h>
#include <stdint.h>

#define IN_F 4096
#define OUT_F 4096
#define M_TOTAL 8192   // 4 * 2048
#define NKT 64         // IN_F / 64

typedef __hip_bfloat16 bf16;
typedef __attribute__((ext_vector_type(8))) short bf16x8;   // 8 bf16 (4 VGPRs)
typedef __attribute__((ext_vector_type(4))) float f32x4;    // MFMA accumulator

// ---------------- kernel 1: fused prep — dequant W (blocks [0,8192)) + cvt x (rest)
__global__ __launch_bounds__(256) void prep(const int* __restrict__ qweight,
                                            const float* __restrict__ scales,
                                            const int* __restrict__ qzeros,
                                            bf16* __restrict__ Wb,
                                            const float* __restrict__ x,
                                            bf16* __restrict__ Xb) {
    int b = blockIdx.x;
    if (b < 8192) {
        int idx = b * 256 + threadIdx.x;            // one int32 (8 nibbles) per thread
        int o = idx >> 9;                           // / (IN_F/8)
        int j = idx & 511;
        int g = j >> 4;                             // (j*8)/128
        int qw = qweight[idx];
        float s = scales[g * OUT_F + o];
        float z = (float)qzeros[g * OUT_F + o];
        union { bf16 h[8]; uint4 q; } out;
#pragma unroll
        for (int k = 0; k < 8; ++k) {
            float w = (float)((qw >> (4 * k)) & 15);
            out.h[k] = __float2bfloat16((w - z) * s);
        }
        *reinterpret_cast<uint4*>(Wb + ((size_t)o * IN_F + j * 8)) = out.q;
    } else {
        int idx = (b - 8192) * 256 + threadIdx.x;   // 8 floats per thread
        const float4* p = reinterpret_cast<const float4*>(x) + (size_t)idx * 2;
        float4 a = p[0], c = p[1];
        union { bf16 h[8]; uint4 q; } o;
        o.h[0] = __float2bfloat16(a.x); o.h[1] = __float2bfloat16(a.y);
        o.h[2] = __float2bfloat16(a.z); o.h[3] = __float2bfloat16(a.w);
        o.h[4] = __float2bfloat16(c.x); o.h[5] = __float2bfloat16(c.y);
        o.h[6] = __float2bfloat16(c.z); o.h[7] = __float2bfloat16(c.w);
        reinterpret_cast<uint4*>(Xb)[idx] = o.q;
    }
}

// ---------------- kernel 2: 256x256 8-phase bf16 GEMM (round-6 proven: 237us GEMM)
// 1-phase-ahead ds_read pipelining: each phase's fragments are read during the
// PREVIOUS phase, right after its MFMA issue, so LGKM0 after the barrier is ~free.
// C(MxN) = A(MxK)*B(NxK)^T + bias. 8 waves (2M x 4N), per-wave 128x64 out.
// Fragment rows: A = MH*128 + wr*64 + m4*16; B = NH*128 + wc*32 + n2*16.
// LDS 128 KiB: buf b at b*65536; A h0/h1 @ +0/+16384, B h0/h1 @ +32768/+49152.
// Swizzle: 16B slot s of row r stored at s ^ (r & 7); pre-swizzled global src.

__device__ __forceinline__ void gload16(const bf16* g, char* l) {
    __builtin_amdgcn_global_load_lds(
        (const __attribute__((address_space(1))) void*)g,
        (__attribute__((address_space(3))) void*)l, 16, 0, 0);
}

// Stage 128 rows x 64 cols bf16 (16 KiB): 8 waves x 2 loads x 64 lanes x 16 B.
__device__ __forceinline__ void stage_half(const bf16* __restrict__ Gt,
                                           char* ldsb, int wave, int lane) {
    const int slog8 = ((lane & 7) ^ (lane >> 3)) * 8;   // pre-swizzled 16B slot
#pragma unroll
    for (int j = 0; j < 2; ++j) {
        int r = wave * 16 + j * 8 + (lane >> 3);        // r & 7 == lane>>3
        gload16(Gt + (size_t)r * IN_F + slog8, ldsb + (wave * 2 + j) * 1024);
    }
}

#define BARRIER() do { asm volatile("" ::: "memory"); \
                       __builtin_amdgcn_s_barrier();  \
                       asm volatile("" ::: "memory"); } while (0)
#define LGKM0()   asm volatile("s_waitcnt lgkmcnt(0)" ::: "memory")
#define VMCNT6()  asm volatile("s_waitcnt vmcnt(6)" ::: "memory")
#define VMCNT0()  asm volatile("s_waitcnt vmcnt(0)" ::: "memory")

// A fragment rows: MH*128 + wr*64 + m4*16 + l15
#define LDA_SET(DST, BUF, MH) do {                                              \
  _Pragma("unroll") for (int m4 = 0; m4 < 4; ++m4)                              \
  _Pragma("unroll") for (int kk = 0; kk < 2; ++kk)                              \
    DST[m4][kk] = *reinterpret_cast<const bf16x8*>(sm + (BUF) * 65536           \
        + (((MH) * 128 + wr * 64 + m4 * 16 + l15) << 7)                         \
        + ((((kk << 2) + lq) ^ l7) << 4));                                      \
} while (0)

// B fragment rows: NH*128 + wc*32 + n2*16 + l15
#define LDB_SET(DST, BUF, NH) do {                                              \
  _Pragma("unroll") for (int n2 = 0; n2 < 2; ++n2)                              \
  _Pragma("unroll") for (int kk = 0; kk < 2; ++kk)                              \
    DST[n2][kk] = *reinterpret_cast<const bf16x8*>(sm + (BUF) * 65536 + 32768   \
        + (((NH) * 128 + wc * 32 + n2 * 16 + l15) << 7)                         \
        + ((((kk << 2) + lq) ^ l7) << 4));                                      \
} while (0)

#define MMA_Q(AF, BFR, MH, NH) do {                                             \
  __builtin_amdgcn_s_setprio(1);                                                \
  _Pragma("unroll") for (int m4 = 0; m4 < 4; ++m4)                              \
  _Pragma("unroll") for (int n2 = 0; n2 < 2; ++n2)                              \
  _Pragma("unroll") for (int kk = 0; kk < 2; ++kk)                              \
    acc[(MH) * 4 + m4][(NH) * 2 + n2] = __builtin_amdgcn_mfma_f32_16x16x32_bf16(\
        AF[m4][kk], BFR[n2][kk], acc[(MH) * 4 + m4][(NH) * 2 + n2], 0, 0, 0);   \
  __builtin_amdgcn_s_setprio(0);                                                \
} while (0)

__global__ __launch_bounds__(512, 2) void gemm256(const bf16* __restrict__ A,   // M x K
                                                  const bf16* __restrict__ B,   // N x K
                                                  const float* __restrict__ bias,
                                                  float* __restrict__ C) {
    extern __shared__ char sm[];
    const int tid  = threadIdx.x;
    const int wave = tid >> 6;
    const int lane = tid & 63;
    const int wr   = wave >> 2;       // 2 M-rows of waves
    const int wc   = wave & 3;        // 4 N-cols of waves
    const int l15  = lane & 15;
    const int lq   = lane >> 4;
    const int l7   = lane & 7;

    // XCD-aware bijective swizzle (nwg = 512, % 8 == 0)
    const int nwg = gridDim.x;
    const int cpx = nwg >> 3;
    const int wg  = blockIdx.x;
    const int swz = (wg & 7) * cpx + (wg >> 3);
    const int bm  = swz >> 4;         // 16 n-tiles (4096/256)
    const int bn  = swz & 15;
    const int m0  = bm * 256;
    const int n0  = bn * 256;

    const bf16* A0 = A + (size_t)m0 * IN_F;          // A h0 rows
    const bf16* A1 = A + (size_t)(m0 + 128) * IN_F;  // A h1 rows
    const bf16* B0 = B + (size_t)n0 * IN_F;
    const bf16* B1 = B + (size_t)(n0 + 128) * IN_F;

    f32x4 acc[8][4];
#pragma unroll
    for (int m = 0; m < 8; ++m)
#pragma unroll
        for (int n = 0; n < 4; ++n) acc[m][n] = (f32x4){0.f, 0.f, 0.f, 0.f};

    bf16x8 af0[4][2], af1[4][2], bfr0[2][2], bfr1[2][2];

    // ---- prologue: tile0 fully + tile1 {Ah0, Ah1, Bh0}; 14 loads in flight
    stage_half(A0,      sm + 0,     wave, lane);   // A(0) h0
    stage_half(A1,      sm + 16384, wave, lane);   // A(0) h1
    stage_half(B0,      sm + 32768, wave, lane);   // B(0) h0
    stage_half(B1,      sm + 49152, wave, lane);   // B(0) h1
    stage_half(A0 + 64, sm + 65536, wave, lane);   // A(1) h0
    stage_half(A1 + 64, sm + 81920, wave, lane);   // A(1) h1
    stage_half(B0 + 64, sm + 98304, wave, lane);   // B(1) h0
    VMCNT6();          // tile0 landed; tile1's 3 halves stay in flight
    BARRIER();
    // pre-read P1's fragments (buf0 t0) — P1's LGKM0 covers them
    LDA_SET(af0, 0, 0);
    LDB_SET(bfr0, 0, 0);

    for (int i = 0; i < 32; ++i) {
        const int t1 = 2 * i + 1;
        const int t2 = 2 * i + 2;
        const int t3 = 2 * i + 3;
        const bool gg = (i < 31);

        // ---- P1: MFMA t0 (MH0,NH0); stage buf1.Bh1(t1); pre-read af1.
        stage_half(B1 + t1 * 64, sm + 114688, wave, lane);
        BARRIER(); LGKM0();
        MMA_Q(af0, bfr0, 0, 0);
        LDA_SET(af1, 0, 1);                                      // for P2
        BARRIER();
        // ---- P2: (MH1,NH0); buf0.Ah0 free (read prev P8) -> stage; pre-read bfr1.
        if (gg) stage_half(A0 + t2 * 64, sm + 0, wave, lane);
        BARRIER(); LGKM0();
        MMA_Q(af1, bfr0, 1, 0);
        LDB_SET(bfr1, 0, 1);                                     // for P3
        BARRIER();
        // ---- P3: (MH0,NH1); buf0.Ah1 free (read P1) -> stage.
        if (gg) stage_half(A1 + t2 * 64, sm + 16384, wave, lane);
        BARRIER(); LGKM0();
        MMA_Q(af0, bfr1, 0, 1);
        BARRIER();
        // ---- P4: (MH1,NH1); buf0.Bh0 free (read prev P8) -> stage.
        if (gg) stage_half(B0 + t2 * 64, sm + 32768, wave, lane);
        BARRIER(); LGKM0();
        MMA_Q(af1, bfr1, 1, 1);
        if (gg) { VMCNT6(); } else { VMCNT0(); }   // tile t1 fully landed
        LDA_SET(af0, 1, 0);                                      // for P5 (buf1)
        LDB_SET(bfr0, 1, 0);
        BARRIER();

        // ---- P5: t1 (buf1) (MH0,NH0); buf0.Bh1 free (read P2) -> stage; pre-read af1.
        if (gg) stage_half(B1 + t2 * 64, sm + 49152, wave, lane);
        BARRIER(); LGKM0();
        MMA_Q(af0, bfr0, 0, 0);
        LDA_SET(af1, 1, 1);                                      // for P6
        BARRIER();
        // ---- P6: (MH1,NH0); buf1.Ah0 free (read P4) -> stage; pre-read bfr1.
        if (gg) stage_half(A0 + t3 * 64, sm + 65536, wave, lane);
        BARRIER(); LGKM0();
        MMA_Q(af1, bfr0, 1, 0);
        LDB_SET(bfr1, 1, 1);                                     // for P7
        BARRIER();
        // ---- P7: (MH0,NH1); buf1.Ah1 free (read P5) -> stage.
        if (gg) stage_half(A1 + t3 * 64, sm + 81920, wave, lane);
        BARRIER(); LGKM0();
        MMA_Q(af0, bfr1, 0, 1);
        BARRIER();
        // ---- P8: (MH1,NH1); buf1.Bh0 free (read P4) -> stage.
        if (gg) stage_half(B0 + t3 * 64, sm + 98304, wave, lane);
        BARRIER(); LGKM0();
        MMA_Q(af1, bfr1, 1, 1);
        if (gg) { VMCNT6(); } else { VMCNT0(); }   // tile t2 fully landed
        if (gg) {
            LDA_SET(af0, 0, 0);                                  // for next-iter P1
            LDB_SET(bfr0, 0, 0);
        }
        BARRIER();
    }

    // ---- epilogue: C/D layout col = lane&15, row = (lane>>4)*4 + reg
    const int crow_base = m0 + wr * 64 + lq * 4;
    const int ccol_base = n0 + wc * 32 + l15;
#pragma unroll
    for (int n = 0; n < 4; ++n) {
        const int NH = n >> 1, n2 = n & 1;
        const int col = ccol_base + NH * 128 + n2 * 16;
        float bv = bias[col];
#pragma unroll
        for (int m = 0; m < 8; ++m) {
            const int MH = m >> 2, m4 = m & 3;
            const int row = crow_base + MH * 128 + m4 * 16;
#pragma unroll
            for (int r = 0; r < 4; ++r)
                C[(size_t)(row + r) * OUT_F + col] = acc[m][n][r] + bv;
        }
    }
}

// ---------------- fallback: fp32 tiled GEMM with on-the-fly dequant (ws too small)
__global__ __launch_bounds__(256) void fallback_gemm(const float* __restrict__ x,
                                                     const int* __restrict__ qweight,
                                                     const float* __restrict__ scales,
                                                     const int* __restrict__ qzeros,
                                                     const float* __restrict__ bias,
                                                     float* __restrict__ out) {
    __shared__ float Asf[64][65];
    __shared__ float Bsf[64][65];
    int bm = blockIdx.x >> 6;
    int bn = blockIdx.x & 63;
    int m0 = bm * 64, n0 = bn * 64;
    int t  = threadIdx.x;
    int tr = t >> 4, tc = t & 15;
    float acc[4][4] = {};
    for (int kt = 0; kt < IN_F; kt += 64) {
#pragma unroll
        for (int i = 0; i < 4; ++i) {
            int idx = t + i * 256;
            int r = idx >> 4, c4 = idx & 15;
            float4 v = *reinterpret_cast<const float4*>(x + (size_t)(m0 + r) * IN_F + kt + c4 * 4);
            Asf[r][c4 * 4 + 0] = v.x; Asf[r][c4 * 4 + 1] = v.y;
            Asf[r][c4 * 4 + 2] = v.z; Asf[r][c4 * 4 + 3] = v.w;
        }
#pragma unroll
        for (int i = 0; i < 2; ++i) {
            int idx = t + i * 256;
            int r = idx >> 3, k8 = idx & 7;
            int kk = kt + k8 * 8;
            int o  = n0 + r;
            int qw = qweight[(size_t)o * (IN_F / 8) + (kk >> 3)];
            int g  = kk >> 7;
            float s = scales[g * OUT_F + o];
            float z = (float)qzeros[g * OUT_F + o];
#pragma unroll
            for (int b = 0; b < 8; ++b)
                Bsf[r][k8 * 8 + b] = ((float)((qw >> (4 * b)) & 15) - z) * s;
        }
        __syncthreads();
#pragma unroll 8
        for (int k = 0; k < 64; ++k) {
            float a[4], bb[4];
#pragma unroll
            for (int i = 0; i < 4; ++i) a[i] = Asf[tr * 4 + i][k];
#pragma unroll
            for (int j = 0; j < 4; ++j) bb[j] = Bsf[tc * 4 + j][k];
#pragma unroll
            for (int i = 0; i < 4; ++i)
#pragma unroll
                for (int j = 0; j < 4; ++j) acc[i][j] += a[i] * bb[j];
        }
        __syncthreads();
    }
#pragma unroll
    for (int i = 0; i < 4; ++i) {
        int row = m0 + tr * 4 + i;
#pragma unroll
        for (int j = 0; j < 4; ++j) {
            int col = n0 + tc * 4 + j;
            out[(size_t)row * OUT_F + col] = acc[i][j] + bias[col];
        }
    }
}

extern "C" void kernel_launch(void* const* d_in, const int* in_sizes, int n_in,
                              void* d_out, int out_size, void* d_ws, size_t ws_size,
                              hipStream_t stream) {
    (void)in_sizes; (void)n_in; (void)out_size;
    const float* x       = (const float*)d_in[0];
    const int*   qweight = (const int*)d_in[1];
    const float* scales  = (const float*)d_in[2];
    const int*   qzeros  = (const int*)d_in[3];
    const float* bias    = (const float*)d_in[4];
    float* out = (float*)d_out;

    const size_t needW = (size_t)OUT_F * IN_F * sizeof(bf16);   // 32 MB
    const size_t needX = (size_t)M_TOTAL * IN_F * sizeof(bf16); // 64 MB

    if (ws_size >= needW + needX) {
        bf16* Wb = (bf16*)d_ws;
        bf16* Xb = (bf16*)((char*)d_ws + needW);
        // fused prep: 8192 dequant blocks + 16384 cvt blocks
        prep<<<8192 + 16384, 256, 0, stream>>>(qweight, scales, qzeros, Wb, x, Xb);
        gemm256<<<(M_TOTAL / 256) * (OUT_F / 256), 512, 131072, stream>>>(Xb, Wb, bias, out);
    } else {
        fallback_gemm<<<(M_TOTAL / 64) * (OUT_F / 64), 256, 0, stream>>>(
            x, qweight, scales, qzeros, bias, out);
    }
}

// Round 10
// 267.771 us; speedup vs baseline: 2.2345x; 1.0217x over previous
//
#include <hip/hip_runtime.h>
#include <hip/hip_bf16.h>
#include <stdint.h>

#define IN_F 4096
#define OUT_F 4096
#define M_TOTAL 8192   // 4 * 2048
#define NKT 64         // IN_F / 64

typedef __hip_bfloat16 bf16;
typedef __attribute__((ext_vector_type(8))) short bf16x8;   // 8 bf16 (4 VGPRs)
typedef __attribute__((ext_vector_type(4))) float f32x4;    // MFMA accumulator

// ---------------- kernel 1: fused prep — dequant W (blocks [0,8192)) + cvt x (rest)
__global__ __launch_bounds__(256) void prep(const int* __restrict__ qweight,
                                            const float* __restrict__ scales,
                                            const int* __restrict__ qzeros,
                                            bf16* __restrict__ Wb,
                                            const float* __restrict__ x,
                                            bf16* __restrict__ Xb) {
    int b = blockIdx.x;
    if (b < 8192) {
        int idx = b * 256 + threadIdx.x;            // one int32 (8 nibbles) per thread
        int o = idx >> 9;                           // / (IN_F/8)
        int j = idx & 511;
        int g = j >> 4;                             // (j*8)/128
        int qw = qweight[idx];
        float s = scales[g * OUT_F + o];
        float z = (float)qzeros[g * OUT_F + o];
        union { bf16 h[8]; uint4 q; } out;
#pragma unroll
        for (int k = 0; k < 8; ++k) {
            float w = (float)((qw >> (4 * k)) & 15);
            out.h[k] = __float2bfloat16((w - z) * s);
        }
        *reinterpret_cast<uint4*>(Wb + ((size_t)o * IN_F + j * 8)) = out.q;
    } else {
        int idx = (b - 8192) * 256 + threadIdx.x;   // 8 floats per thread
        const float4* p = reinterpret_cast<const float4*>(x) + (size_t)idx * 2;
        float4 a = p[0], c = p[1];
        union { bf16 h[8]; uint4 q; } o;
        o.h[0] = __float2bfloat16(a.x); o.h[1] = __float2bfloat16(a.y);
        o.h[2] = __float2bfloat16(a.z); o.h[3] = __float2bfloat16(a.w);
        o.h[4] = __float2bfloat16(c.x); o.h[5] = __float2bfloat16(c.y);
        o.h[6] = __float2bfloat16(c.z); o.h[7] = __float2bfloat16(c.w);
        reinterpret_cast<uint4*>(Xb)[idx] = o.q;
    }
}

// ---------------- kernel 2: 256x256 8-phase bf16 GEMM (round-6 base, 237us) with
// SINGLE barrier per phase: the opening barrier of each phase is removed — every
// stage is >=1 closing barrier after its region's last pre-read (ledger-checked
// pairwise), and within-phase stage targets are disjoint from same-phase reads.
// 1-phase-ahead ds_read pipelining retained (LGKM0 waits ~600-cyc-old reads).
// C(MxN) = A(MxK)*B(NxK)^T + bias. 8 waves (2M x 4N), per-wave 128x64 out.
// Fragment rows: A = MH*128 + wr*64 + m4*16; B = NH*128 + wc*32 + n2*16.
// LDS 128 KiB: buf b at b*65536; A h0/h1 @ +0/+16384, B h0/h1 @ +32768/+49152.
// Swizzle: 16B slot s of row r stored at s ^ (r & 7); pre-swizzled global src.

__device__ __forceinline__ void gload16(const bf16* g, char* l) {
    __builtin_amdgcn_global_load_lds(
        (const __attribute__((address_space(1))) void*)g,
        (__attribute__((address_space(3))) void*)l, 16, 0, 0);
}

// Stage 128 rows x 64 cols bf16 (16 KiB): 8 waves x 2 loads x 64 lanes x 16 B.
__device__ __forceinline__ void stage_half(const bf16* __restrict__ Gt,
                                           char* ldsb, int wave, int lane) {
    const int slog8 = ((lane & 7) ^ (lane >> 3)) * 8;   // pre-swizzled 16B slot
#pragma unroll
    for (int j = 0; j < 2; ++j) {
        int r = wave * 16 + j * 8 + (lane >> 3);        // r & 7 == lane>>3
        gload16(Gt + (size_t)r * IN_F + slog8, ldsb + (wave * 2 + j) * 1024);
    }
}

#define BARRIER() do { asm volatile("" ::: "memory"); \
                       __builtin_amdgcn_s_barrier();  \
                       asm volatile("" ::: "memory"); } while (0)
#define LGKM0()   asm volatile("s_waitcnt lgkmcnt(0)" ::: "memory")
#define VMCNT6()  asm volatile("s_waitcnt vmcnt(6)" ::: "memory")
#define VMCNT0()  asm volatile("s_waitcnt vmcnt(0)" ::: "memory")

// A fragment rows: MH*128 + wr*64 + m4*16 + l15
#define LDA_SET(DST, BUF, MH) do {                                              \
  _Pragma("unroll") for (int m4 = 0; m4 < 4; ++m4)                              \
  _Pragma("unroll") for (int kk = 0; kk < 2; ++kk)                              \
    DST[m4][kk] = *reinterpret_cast<const bf16x8*>(sm + (BUF) * 65536           \
        + (((MH) * 128 + wr * 64 + m4 * 16 + l15) << 7)                         \
        + ((((kk << 2) + lq) ^ l7) << 4));                                      \
} while (0)

// B fragment rows: NH*128 + wc*32 + n2*16 + l15
#define LDB_SET(DST, BUF, NH) do {                                              \
  _Pragma("unroll") for (int n2 = 0; n2 < 2; ++n2)                              \
  _Pragma("unroll") for (int kk = 0; kk < 2; ++kk)                              \
    DST[n2][kk] = *reinterpret_cast<const bf16x8*>(sm + (BUF) * 65536 + 32768   \
        + (((NH) * 128 + wc * 32 + n2 * 16 + l15) << 7)                         \
        + ((((kk << 2) + lq) ^ l7) << 4));                                      \
} while (0)

#define MMA_Q(AF, BFR, MH, NH) do {                                             \
  __builtin_amdgcn_s_setprio(1);                                                \
  _Pragma("unroll") for (int m4 = 0; m4 < 4; ++m4)                              \
  _Pragma("unroll") for (int n2 = 0; n2 < 2; ++n2)                              \
  _Pragma("unroll") for (int kk = 0; kk < 2; ++kk)                              \
    acc[(MH) * 4 + m4][(NH) * 2 + n2] = __builtin_amdgcn_mfma_f32_16x16x32_bf16(\
        AF[m4][kk], BFR[n2][kk], acc[(MH) * 4 + m4][(NH) * 2 + n2], 0, 0, 0);   \
  __builtin_amdgcn_s_setprio(0);                                                \
} while (0)

__global__ __launch_bounds__(512, 2) void gemm256(const bf16* __restrict__ A,   // M x K
                                                  const bf16* __restrict__ B,   // N x K
                                                  const float* __restrict__ bias,
                                                  float* __restrict__ C) {
    extern __shared__ char sm[];
    const int tid  = threadIdx.x;
    const int wave = tid >> 6;
    const int lane = tid & 63;
    const int wr   = wave >> 2;       // 2 M-rows of waves
    const int wc   = wave & 3;        // 4 N-cols of waves
    const int l15  = lane & 15;
    const int lq   = lane >> 4;
    const int l7   = lane & 7;

    // XCD-aware bijective swizzle (nwg = 512, % 8 == 0)
    const int nwg = gridDim.x;
    const int cpx = nwg >> 3;
    const int wg  = blockIdx.x;
    const int swz = (wg & 7) * cpx + (wg >> 3);
    const int bm  = swz >> 4;         // 16 n-tiles (4096/256)
    const int bn  = swz & 15;
    const int m0  = bm * 256;
    const int n0  = bn * 256;

    const bf16* A0 = A + (size_t)m0 * IN_F;          // A h0 rows
    const bf16* A1 = A + (size_t)(m0 + 128) * IN_F;  // A h1 rows
    const bf16* B0 = B + (size_t)n0 * IN_F;
    const bf16* B1 = B + (size_t)(n0 + 128) * IN_F;

    f32x4 acc[8][4];
#pragma unroll
    for (int m = 0; m < 8; ++m)
#pragma unroll
        for (int n = 0; n < 4; ++n) acc[m][n] = (f32x4){0.f, 0.f, 0.f, 0.f};

    bf16x8 af0[4][2], af1[4][2], bfr0[2][2], bfr1[2][2];

    // ---- prologue: tile0 fully + tile1 {Ah0, Ah1, Bh0}; 14 loads in flight
    stage_half(A0,      sm + 0,     wave, lane);   // A(0) h0
    stage_half(A1,      sm + 16384, wave, lane);   // A(0) h1
    stage_half(B0,      sm + 32768, wave, lane);   // B(0) h0
    stage_half(B1,      sm + 49152, wave, lane);   // B(0) h1
    stage_half(A0 + 64, sm + 65536, wave, lane);   // A(1) h0
    stage_half(A1 + 64, sm + 81920, wave, lane);   // A(1) h1
    stage_half(B0 + 64, sm + 98304, wave, lane);   // B(1) h0
    VMCNT6();          // tile0 landed; tile1's 3 halves stay in flight
    BARRIER();
    // pre-read P1's fragments (buf0 t0) — P1's LGKM0 covers them
    LDA_SET(af0, 0, 0);
    LDB_SET(bfr0, 0, 0);

    for (int i = 0; i < 32; ++i) {
        const int t1 = 2 * i + 1;
        const int t2 = 2 * i + 2;
        const int t3 = 2 * i + 3;
        const bool gg = (i < 31);

        // ---- P1: MFMA t0 (MH0,NH0); stage buf1.Bh1(t1); pre-read af1.
        stage_half(B1 + t1 * 64, sm + 114688, wave, lane);
        LGKM0();
        MMA_Q(af0, bfr0, 0, 0);
        LDA_SET(af1, 0, 1);                                      // for P2
        BARRIER();
        // ---- P2: (MH1,NH0); buf0.Ah0 free (read prev P8, 2 barriers ago) -> stage.
        if (gg) stage_half(A0 + t2 * 64, sm + 0, wave, lane);
        LGKM0();
        MMA_Q(af1, bfr0, 1, 0);
        LDB_SET(bfr1, 0, 1);                                     // for P3
        BARRIER();
        // ---- P3: (MH0,NH1); buf0.Ah1 free (read P1's pre-read... last t0 read P2-prev) -> stage.
        if (gg) stage_half(A1 + t2 * 64, sm + 16384, wave, lane);
        LGKM0();
        MMA_Q(af0, bfr1, 0, 1);
        BARRIER();
        // ---- P4: (MH1,NH1); buf0.Bh0 free (read prev P8) -> stage.
        if (gg) stage_half(B0 + t2 * 64, sm + 32768, wave, lane);
        LGKM0();
        MMA_Q(af1, bfr1, 1, 1);
        if (gg) { VMCNT6(); } else { VMCNT0(); }   // tile t1 fully landed
        LDA_SET(af0, 1, 0);                                      // for P5 (buf1)
        LDB_SET(bfr0, 1, 0);
        BARRIER();

        // ---- P5: t1 (buf1) (MH0,NH0); buf0.Bh1 free (read P2) -> stage.
        if (gg) stage_half(B1 + t2 * 64, sm + 49152, wave, lane);
        LGKM0();
        MMA_Q(af0, bfr0, 0, 0);
        LDA_SET(af1, 1, 1);                                      // for P6
        BARRIER();
        // ---- P6: (MH1,NH0); buf1.Ah0 free (read P4) -> stage.
        if (gg) stage_half(A0 + t3 * 64, sm + 65536, wave, lane);
        LGKM0();
        MMA_Q(af1, bfr0, 1, 0);
        LDB_SET(bfr1, 1, 1);                                     // for P7
        BARRIER();
        // ---- P7: (MH0,NH1); buf1.Ah1 free (read P5) -> stage.
        if (gg) stage_half(A1 + t3 * 64, sm + 81920, wave, lane);
        LGKM0();
        MMA_Q(af0, bfr1, 0, 1);
        BARRIER();
        // ---- P8: (MH1,NH1); buf1.Bh0 free (read P4) -> stage.
        if (gg) stage_half(B0 + t3 * 64, sm + 98304, wave, lane);
        LGKM0();
        MMA_Q(af1, bfr1, 1, 1);
        if (gg) { VMCNT6(); } else { VMCNT0(); }   // tile t2 fully landed
        if (gg) {
            LDA_SET(af0, 0, 0);                                  // for next-iter P1
            LDB_SET(bfr0, 0, 0);
        }
        BARRIER();
    }

    // ---- epilogue: C/D layout col = lane&15, row = (lane>>4)*4 + reg
    const int crow_base = m0 + wr * 64 + lq * 4;
    const int ccol_base = n0 + wc * 32 + l15;
#pragma unroll
    for (int n = 0; n < 4; ++n) {
        const int NH = n >> 1, n2 = n & 1;
        const int col = ccol_base + NH * 128 + n2 * 16;
        float bv = bias[col];
#pragma unroll
        for (int m = 0; m < 8; ++m) {
            const int MH = m >> 2, m4 = m & 3;
            const int row = crow_base + MH * 128 + m4 * 16;
#pragma unroll
            for (int r = 0; r < 4; ++r)
                C[(size_t)(row + r) * OUT_F + col] = acc[m][n][r] + bv;
        }
    }
}

// ---------------- fallback: fp32 tiled GEMM with on-the-fly dequant (ws too small)
__global__ __launch_bounds__(256) void fallback_gemm(const float* __restrict__ x,
                                                     const int* __restrict__ qweight,
                                                     const float* __restrict__ scales,
                                                     const int* __restrict__ qzeros,
                                                     const float* __restrict__ bias,
                                                     float* __restrict__ out) {
    __shared__ float Asf[64][65];
    __shared__ float Bsf[64][65];
    int bm = blockIdx.x >> 6;
    int bn = blockIdx.x & 63;
    int m0 = bm * 64, n0 = bn * 64;
    int t  = threadIdx.x;
    int tr = t >> 4, tc = t & 15;
    float acc[4][4] = {};
    for (int kt = 0; kt < IN_F; kt += 64) {
#pragma unroll
        for (int i = 0; i < 4; ++i) {
            int idx = t + i * 256;
            int r = idx >> 4, c4 = idx & 15;
            float4 v = *reinterpret_cast<const float4*>(x + (size_t)(m0 + r) * IN_F + kt + c4 * 4);
            Asf[r][c4 * 4 + 0] = v.x; Asf[r][c4 * 4 + 1] = v.y;
            Asf[r][c4 * 4 + 2] = v.z; Asf[r][c4 * 4 + 3] = v.w;
        }
#pragma unroll
        for (int i = 0; i < 2; ++i) {
            int idx = t + i * 256;
            int r = idx >> 3, k8 = idx & 7;
            int kk = kt + k8 * 8;
            int o  = n0 + r;
            int qw = qweight[(size_t)o * (IN_F / 8) + (kk >> 3)];
            int g  = kk >> 7;
            float s = scales[g * OUT_F + o];
            float z = (float)qzeros[g * OUT_F + o];
#pragma unroll
            for (int b = 0; b < 8; ++b)
                Bsf[r][k8 * 8 + b] = ((float)((qw >> (4 * b)) & 15) - z) * s;
        }
        __syncthreads();
#pragma unroll 8
        for (int k = 0; k < 64; ++k) {
            float a[4], bb[4];
#pragma unroll
            for (int i = 0; i < 4; ++i) a[i] = Asf[tr * 4 + i][k];
#pragma unroll
            for (int j = 0; j < 4; ++j) bb[j] = Bsf[tc * 4 + j][k];
#pragma unroll
            for (int i = 0; i < 4; ++i)
#pragma unroll
                for (int j = 0; j < 4; ++j) acc[i][j] += a[i] * bb[j];
        }
        __syncthreads();
    }
#pragma unroll
    for (int i = 0; i < 4; ++i) {
        int row = m0 + tr * 4 + i;
#pragma unroll
        for (int j = 0; j < 4; ++j) {
            int col = n0 + tc * 4 + j;
            out[(size_t)row * OUT_F + col] = acc[i][j] + bias[col];
        }
    }
}

extern "C" void kernel_launch(void* const* d_in, const int* in_sizes, int n_in,
                              void* d_out, int out_size, void* d_ws, size_t ws_size,
                              hipStream_t stream) {
    (void)in_sizes; (void)n_in; (void)out_size;
    const float* x       = (const float*)d_in[0];
    const int*   qweight = (const int*)d_in[1];
    const float* scales  = (const float*)d_in[2];
    const int*   qzeros  = (const int*)d_in[3];
    const float* bias    = (const float*)d_in[4];
    float* out = (float*)d_out;

    const size_t needW = (size_t)OUT_F * IN_F * sizeof(bf16);   // 32 MB
    const size_t needX = (size_t)M_TOTAL * IN_F * sizeof(bf16); // 64 MB

    if (ws_size >= needW + needX) {
        bf16* Wb = (bf16*)d_ws;
        bf16* Xb = (bf16*)((char*)d_ws + needW);
        // fused prep: 8192 dequant blocks + 16384 cvt blocks
        prep<<<8192 + 16384, 256, 0, stream>>>(qweight, scales, qzeros, Wb, x, Xb);
        gemm256<<<(M_TOTAL / 256) * (OUT_F / 256), 512, 131072, stream>>>(Xb, Wb, bias, out);
    } else {
        fallback_gemm<<<(M_TOTAL / 64) * (OUT_F / 64), 256, 0, stream>>>(
            x, qweight, scales, qzeros, bias, out);
    }
}